// Round 2
// baseline (567.070 us; speedup 1.0000x reference)
//
#include <hip/hip_runtime.h>

#define N_NODES 50000
#define N_EDGES 1600000
#define D_IN    256
#define HS      32

// ---------------------------------------------------------------------------
// Kernel 1: fused Q/K/V projection with W staged in LDS.
// W total is 96 KB (3 mats x 256 x 32 fp32) -> thrashes 32 KB L1 against the
// streaming X reads. Stage it in LDS in two 48 KB k-chunks instead.
// LDS layout [kk][mat*32+j]: lane j reads bank j -> conflict-free.
// Thread layout: j = t&31 (output col), g = t>>5 (row group of 8 rows);
// block covers 64 rows.
// ---------------------------------------------------------------------------
__global__ __launch_bounds__(256) void proj_kernel(
    const float* __restrict__ X,  const float* __restrict__ Wq,
    const float* __restrict__ Wk, const float* __restrict__ Wv,
    float* __restrict__ Q, float* __restrict__ K, float* __restrict__ V)
{
    __shared__ float wlds[128 * 96];   // 48 KB: [kk 0..127][mat*32+j]

    const int t = threadIdx.x;
    const int j = t & 31;
    const int g = t >> 5;
    const int row0 = blockIdx.x * 64 + g * 8;

    float acc[3][8];
#pragma unroll
    for (int m = 0; m < 3; m++)
#pragma unroll
        for (int i = 0; i < 8; i++) acc[m][i] = 0.f;

    int rows[8];
#pragma unroll
    for (int i = 0; i < 8; i++) {
        int r = row0 + i;
        rows[i] = (r < N_NODES) ? r : (N_NODES - 1);  // clamp; OOB never stored
    }

    for (int chunk = 0; chunk < 2; chunk++) {
        __syncthreads();
        // cooperative W-chunk load: 128 k x 32 j per matrix
        for (int idx = t; idx < 128 * 32; idx += 256) {
            const int kk = idx >> 5, jj = idx & 31;
            const int k = chunk * 128 + kk;
            wlds[kk * 96 + jj]      = Wq[k * HS + jj];
            wlds[kk * 96 + 32 + jj] = Wk[k * HS + jj];
            wlds[kk * 96 + 64 + jj] = Wv[k * HS + jj];
        }
        __syncthreads();

        for (int k4 = 0; k4 < 32; k4++) {
            float4 xv[8];
#pragma unroll
            for (int i = 0; i < 8; i++)
                xv[i] = *(const float4*)(X + (size_t)rows[i] * D_IN
                                           + chunk * 128 + k4 * 4);
#pragma unroll
            for (int kk = 0; kk < 4; kk++) {
                const int kl = (k4 * 4 + kk) * 96;
                const float wq = wlds[kl + j];
                const float wk = wlds[kl + 32 + j];
                const float wv = wlds[kl + 64 + j];
#pragma unroll
                for (int i = 0; i < 8; i++) {
                    const float x = ((const float*)&xv[i])[kk];
                    acc[0][i] += x * wq;
                    acc[1][i] += x * wk;
                    acc[2][i] += x * wv;
                }
            }
        }
    }
#pragma unroll
    for (int i = 0; i < 8; i++) {
        const int r = row0 + i;
        if (r < N_NODES) {
            Q[r * HS + j] = acc[0][i];
            K[r * HS + j] = acc[1][i];
            V[r * HS + j] = acc[2][i];
        }
    }
}

// ---------------------------------------------------------------------------
// CSR build: histogram -> exclusive scan -> scatter (sort cols by query row).
// ---------------------------------------------------------------------------
__global__ __launch_bounds__(256) void hist_kernel(
    const int* __restrict__ er, int* __restrict__ cnt)
{
    const int e = blockIdx.x * blockDim.x + threadIdx.x;
    if (e < N_EDGES) atomicAdd(&cnt[er[e]], 1);
}

// single workgroup; two-phase: per-thread chunk sums -> block scan -> emit
__global__ __launch_bounds__(256) void scan_kernel(
    const int* __restrict__ cnt, int* __restrict__ rowptr, int* __restrict__ cnt2)
{
    __shared__ int sums[256];
    const int T = 256;
    const int per = (N_NODES + T - 1) / T;   // 196
    const int t = threadIdx.x;
    const int base = t * per;

    int s = 0;
    for (int i = 0; i < per; i++) {
        const int idx = base + i;
        if (idx < N_NODES) s += cnt[idx];
    }
    sums[t] = s;
    __syncthreads();
    // Hillis-Steele inclusive scan
    for (int ofs = 1; ofs < T; ofs <<= 1) {
        const int v = (t >= ofs) ? sums[t - ofs] : 0;
        __syncthreads();
        sums[t] += v;
        __syncthreads();
    }
    int off = (t == 0) ? 0 : sums[t - 1];
    for (int i = 0; i < per; i++) {
        const int idx = base + i;
        if (idx < N_NODES) {
            rowptr[idx] = off;
            cnt2[idx]   = off;
            off += cnt[idx];
        }
    }
    if (t == T - 1) rowptr[N_NODES] = off;
}

__global__ __launch_bounds__(256) void scatter_kernel(
    const int* __restrict__ er, const int* __restrict__ ec,
    int* __restrict__ cnt2, int* __restrict__ col_sorted)
{
    const int e = blockIdx.x * blockDim.x + threadIdx.x;
    if (e < N_EDGES) {
        const int pos = atomicAdd(&cnt2[er[e]], 1);
        col_sorted[pos] = ec[e];
    }
}

// ---------------------------------------------------------------------------
// Kernel 3: row-parallel aggregation. One wave per row; lanes 0..31 = half 0,
// lanes 32..63 = half 1; each half owns every other edge of the row. Q row in
// registers, accumulate num/denom in registers, one coalesced write per row.
// No atomics anywhere. 2x unroll for gather ILP.
// ---------------------------------------------------------------------------
__global__ __launch_bounds__(256) void aggregate_kernel(
    const int* __restrict__ rowptr, const int* __restrict__ col,
    const float* __restrict__ Q, const float* __restrict__ K,
    const float* __restrict__ V, float* __restrict__ out)
{
    const int lane = threadIdx.x & 63;
    const int r    = (blockIdx.x * blockDim.x + threadIdx.x) >> 6;  // wave id
    if (r >= N_NODES) return;
    const int j = lane & 31;
    const int h = lane >> 5;

    const float q = Q[r * HS + j];
    const int start = rowptr[r];
    const int end   = rowptr[r + 1];
    const float scale = 0.17677669529663687f;  // 1/sqrt(32)

    float accN = 0.f, accD = 0.f;
    int e = start + h;
    // 2 edges per half per iteration (4 per wave): independent gathers
    for (; e + 2 < end; e += 4) {
        const int c0 = col[e];
        const int c1 = col[e + 2];
        const float k0 = K[c0 * HS + j];
        const float v0 = V[c0 * HS + j];
        const float k1 = K[c1 * HS + j];
        const float v1 = V[c1 * HS + j];
        float p0 = q * k0;
        float p1 = q * k1;
#pragma unroll
        for (int ofs = 1; ofs < 32; ofs <<= 1) {
            p0 += __shfl_xor(p0, ofs, 64);
            p1 += __shfl_xor(p1, ofs, 64);
        }
        const float ex0 = __expf(p0 * scale);
        const float ex1 = __expf(p1 * scale);
        accD += ex0 + ex1;
        accN += ex0 * v0 + ex1 * v1;
    }
    if (e < end) {
        const int c0 = col[e];
        const float k0 = K[c0 * HS + j];
        const float v0 = V[c0 * HS + j];
        float p0 = q * k0;
#pragma unroll
        for (int ofs = 1; ofs < 32; ofs <<= 1)
            p0 += __shfl_xor(p0, ofs, 64);
        const float ex0 = __expf(p0 * scale);
        accD += ex0;
        accN += ex0 * v0;
    }
    // combine the two halves
    accN += __shfl_xor(accN, 32, 64);
    accD += __shfl_xor(accD, 32, 64);
    if (h == 0)
        out[r * HS + j] = (accD > 0.f) ? accN / accD : 0.f;
}

extern "C" void kernel_launch(void* const* d_in, const int* in_sizes, int n_in,
                              void* d_out, int out_size, void* d_ws, size_t ws_size,
                              hipStream_t stream)
{
    const float* X  = (const float*)d_in[0];
    const float* Wq = (const float*)d_in[1];
    const float* Wk = (const float*)d_in[2];
    const float* Wv = (const float*)d_in[3];
    const int*   ei = (const int*)d_in[4];
    const int* er = ei;             // edge_index[0] (query rows)
    const int* ec = ei + N_EDGES;   // edge_index[1] (key/value cols)

    float* out = (float*)d_out;

    // workspace layout (~26.2 MB):
    // Q | K | V | cnt | rowptr | cnt2 | col_sorted
    float* Q      = (float*)d_ws;
    float* K      = Q + (size_t)N_NODES * HS;
    float* V      = K + (size_t)N_NODES * HS;
    int* cnt      = (int*)(V + (size_t)N_NODES * HS);
    int* rowptr   = cnt + N_NODES;
    int* cnt2     = rowptr + (N_NODES + 1);
    int* col_sorted = cnt2 + N_NODES;

    hipMemsetAsync(cnt, 0, (size_t)N_NODES * sizeof(int), stream);

    proj_kernel<<<(N_NODES + 63) / 64, 256, 0, stream>>>(X, Wq, Wk, Wv, Q, K, V);

    hist_kernel<<<(N_EDGES + 255) / 256, 256, 0, stream>>>(er, cnt);
    scan_kernel<<<1, 256, 0, stream>>>(cnt, rowptr, cnt2);
    scatter_kernel<<<(N_EDGES + 255) / 256, 256, 0, stream>>>(er, ec, cnt2, col_sorted);

    // one wave per row: 50000 waves = 12500 blocks of 256
    aggregate_kernel<<<(N_NODES * 64 + 255) / 256, 256, 0, stream>>>(
        rowptr, col_sorted, Q, K, V, out);
}

// Round 3
// 436.986 us; speedup vs baseline: 1.2977x; 1.2977x over previous
//
#include <hip/hip_runtime.h>

#define N_NODES 50000
#define N_EDGES 1600000
#define D_IN    256
#define HS      32
#define SCAN_B  196   // ceil(N_NODES / 256)

// ---------------------------------------------------------------------------
// Kernel 1: fused Q/K/V projection with W staged in LDS.
// Writes Q as [N][32] and KV interleaved as float2[N][32] (x=K, y=V) so the
// aggregate kernel does one 8B gather per (edge,lane) instead of two 4B ones.
// ---------------------------------------------------------------------------
__global__ __launch_bounds__(256) void proj_kernel(
    const float* __restrict__ X,  const float* __restrict__ Wq,
    const float* __restrict__ Wk, const float* __restrict__ Wv,
    float* __restrict__ Q, float2* __restrict__ KV)
{
    __shared__ float wlds[128 * 96];   // 48 KB: [kk 0..127][mat*32+j]

    const int t = threadIdx.x;
    const int j = t & 31;
    const int g = t >> 5;
    const int row0 = blockIdx.x * 64 + g * 8;

    float acc[3][8];
#pragma unroll
    for (int m = 0; m < 3; m++)
#pragma unroll
        for (int i = 0; i < 8; i++) acc[m][i] = 0.f;

    int rows[8];
#pragma unroll
    for (int i = 0; i < 8; i++) {
        int r = row0 + i;
        rows[i] = (r < N_NODES) ? r : (N_NODES - 1);  // clamp; OOB never stored
    }

    for (int chunk = 0; chunk < 2; chunk++) {
        __syncthreads();
        for (int idx = t; idx < 128 * 32; idx += 256) {
            const int kk = idx >> 5, jj = idx & 31;
            const int k = chunk * 128 + kk;
            wlds[kk * 96 + jj]      = Wq[k * HS + jj];
            wlds[kk * 96 + 32 + jj] = Wk[k * HS + jj];
            wlds[kk * 96 + 64 + jj] = Wv[k * HS + jj];
        }
        __syncthreads();

        for (int k4 = 0; k4 < 32; k4++) {
            float4 xv[8];
#pragma unroll
            for (int i = 0; i < 8; i++)
                xv[i] = *(const float4*)(X + (size_t)rows[i] * D_IN
                                           + chunk * 128 + k4 * 4);
#pragma unroll
            for (int kk = 0; kk < 4; kk++) {
                const int kl = (k4 * 4 + kk) * 96;
                const float wq = wlds[kl + j];
                const float wk = wlds[kl + 32 + j];
                const float wv = wlds[kl + 64 + j];
#pragma unroll
                for (int i = 0; i < 8; i++) {
                    const float x = ((const float*)&xv[i])[kk];
                    acc[0][i] += x * wq;
                    acc[1][i] += x * wk;
                    acc[2][i] += x * wv;
                }
            }
        }
    }
#pragma unroll
    for (int i = 0; i < 8; i++) {
        const int r = row0 + i;
        if (r < N_NODES) {
            Q[r * HS + j]  = acc[0][i];
            KV[r * HS + j] = make_float2(acc[1][i], acc[2][i]);
        }
    }
}

// ---------------------------------------------------------------------------
// CSR build: histogram -> hierarchical exclusive scan -> scatter.
// ---------------------------------------------------------------------------
__global__ __launch_bounds__(256) void hist_kernel(
    const int* __restrict__ er, int* __restrict__ cnt)
{
    const int e = blockIdx.x * blockDim.x + threadIdx.x;
    if (e < N_EDGES) atomicAdd(&cnt[er[e]], 1);
}

// 196 blocks x 256: block b sums cnt[b*256 .. b*256+255] -> bsum[b]
__global__ __launch_bounds__(256) void blocksum_kernel(
    const int* __restrict__ cnt, int* __restrict__ bsum)
{
    __shared__ int red[256];
    const int t = threadIdx.x;
    const int i = blockIdx.x * 256 + t;
    red[t] = (i < N_NODES) ? cnt[i] : 0;
    __syncthreads();
#pragma unroll
    for (int ofs = 128; ofs > 0; ofs >>= 1) {
        if (t < ofs) red[t] += red[t + ofs];
        __syncthreads();
    }
    if (t == 0) bsum[blockIdx.x] = red[0];
}

// 1 block x 256: exclusive-scan the 196 block sums in LDS (no global loops)
__global__ __launch_bounds__(256) void scanbsum_kernel(int* __restrict__ bsum)
{
    __shared__ int s[256];
    const int t = threadIdx.x;
    const int v = (t < SCAN_B) ? bsum[t] : 0;
    s[t] = v;
    __syncthreads();
#pragma unroll
    for (int ofs = 1; ofs < 256; ofs <<= 1) {
        const int u = (t >= ofs) ? s[t - ofs] : 0;
        __syncthreads();
        s[t] += u;
        __syncthreads();
    }
    if (t < SCAN_B) bsum[t] = s[t] - v;   // exclusive
}

// 196 blocks x 256: per-block exclusive scan + block offset -> rowptr, cnt2
__global__ __launch_bounds__(256) void scanwrite_kernel(
    const int* __restrict__ cnt, const int* __restrict__ bsum,
    int* __restrict__ rowptr, int* __restrict__ cnt2)
{
    __shared__ int s[256];
    const int t = threadIdx.x;
    const int i = blockIdx.x * 256 + t;
    const int v = (i < N_NODES) ? cnt[i] : 0;
    s[t] = v;
    __syncthreads();
#pragma unroll
    for (int ofs = 1; ofs < 256; ofs <<= 1) {
        const int u = (t >= ofs) ? s[t - ofs] : 0;
        __syncthreads();
        s[t] += u;
        __syncthreads();
    }
    if (i < N_NODES) {
        const int off = s[t] - v + bsum[blockIdx.x];
        rowptr[i] = off;
        cnt2[i]   = off;
    }
    if (i == 0) rowptr[N_NODES] = N_EDGES;  // every edge has a valid row
}

__global__ __launch_bounds__(256) void scatter_kernel(
    const int* __restrict__ er, const int* __restrict__ ec,
    int* __restrict__ cnt2, int* __restrict__ col_sorted)
{
    const int e = blockIdx.x * blockDim.x + threadIdx.x;
    if (e < N_EDGES) {
        const int pos = atomicAdd(&cnt2[er[e]], 1);
        col_sorted[pos] = ec[e];
    }
}

// ---------------------------------------------------------------------------
// Kernel 3: row-parallel aggregation. One wave per row; halves own alternate
// edges; KV gathered as float2; all accumulation in registers; no atomics.
// ---------------------------------------------------------------------------
__global__ __launch_bounds__(256) void aggregate_kernel(
    const int* __restrict__ rowptr, const int* __restrict__ col,
    const float* __restrict__ Q, const float2* __restrict__ KV,
    float* __restrict__ out)
{
    const int lane = threadIdx.x & 63;
    const int r    = (blockIdx.x * blockDim.x + threadIdx.x) >> 6;  // wave id
    if (r >= N_NODES) return;
    const int j = lane & 31;
    const int h = lane >> 5;

    const float q = Q[r * HS + j];
    const int start = rowptr[r];
    const int end   = rowptr[r + 1];
    const float scale = 0.17677669529663687f;  // 1/sqrt(32)

    float accN = 0.f, accD = 0.f;
    int e = start + h;
    for (; e + 2 < end; e += 4) {
        const int c0 = col[e];
        const int c1 = col[e + 2];
        const float2 kv0 = KV[c0 * HS + j];
        const float2 kv1 = KV[c1 * HS + j];
        float p0 = q * kv0.x;
        float p1 = q * kv1.x;
#pragma unroll
        for (int ofs = 1; ofs < 32; ofs <<= 1) {
            p0 += __shfl_xor(p0, ofs, 64);
            p1 += __shfl_xor(p1, ofs, 64);
        }
        const float ex0 = __expf(p0 * scale);
        const float ex1 = __expf(p1 * scale);
        accD += ex0 + ex1;
        accN += ex0 * kv0.y + ex1 * kv1.y;
    }
    if (e < end) {
        const int c0 = col[e];
        const float2 kv0 = KV[c0 * HS + j];
        float p0 = q * kv0.x;
#pragma unroll
        for (int ofs = 1; ofs < 32; ofs <<= 1)
            p0 += __shfl_xor(p0, ofs, 64);
        const float ex0 = __expf(p0 * scale);
        accD += ex0;
        accN += ex0 * kv0.y;
    }
    accN += __shfl_xor(accN, 32, 64);
    accD += __shfl_xor(accD, 32, 64);
    if (h == 0)
        out[r * HS + j] = (accD > 0.f) ? accN / accD : 0.f;
}

extern "C" void kernel_launch(void* const* d_in, const int* in_sizes, int n_in,
                              void* d_out, int out_size, void* d_ws, size_t ws_size,
                              hipStream_t stream)
{
    const float* X  = (const float*)d_in[0];
    const float* Wq = (const float*)d_in[1];
    const float* Wk = (const float*)d_in[2];
    const float* Wv = (const float*)d_in[3];
    const int*   ei = (const int*)d_in[4];
    const int* er = ei;             // edge_index[0] (query rows)
    const int* ec = ei + N_EDGES;   // edge_index[1] (key/value cols)

    float* out = (float*)d_out;

    // workspace layout (~26.3 MB):
    // Q | KV(float2) | cnt | rowptr | cnt2 | bsum | col_sorted
    float*  Q        = (float*)d_ws;
    float2* KV       = (float2*)(Q + (size_t)N_NODES * HS);
    int* cnt         = (int*)(KV + (size_t)N_NODES * HS);
    int* rowptr      = cnt + N_NODES;
    int* cnt2        = rowptr + (N_NODES + 1);
    int* bsum        = cnt2 + N_NODES;
    int* col_sorted  = bsum + 256;

    hipMemsetAsync(cnt, 0, (size_t)N_NODES * sizeof(int), stream);

    proj_kernel<<<(N_NODES + 63) / 64, 256, 0, stream>>>(X, Wq, Wk, Wv, Q, KV);

    hist_kernel<<<(N_EDGES + 255) / 256, 256, 0, stream>>>(er, cnt);
    blocksum_kernel<<<SCAN_B, 256, 0, stream>>>(cnt, bsum);
    scanbsum_kernel<<<1, 256, 0, stream>>>(bsum);
    scanwrite_kernel<<<SCAN_B, 256, 0, stream>>>(cnt, bsum, rowptr, cnt2);
    scatter_kernel<<<(N_EDGES + 255) / 256, 256, 0, stream>>>(er, ec, cnt2, col_sorted);

    aggregate_kernel<<<(N_NODES * 64 + 255) / 256, 256, 0, stream>>>(
        rowptr, col_sorted, Q, KV, out);
}

// Round 4
// 281.774 us; speedup vs baseline: 2.0125x; 1.5508x over previous
//
#include <hip/hip_runtime.h>

#define N_NODES 50000
#define N_EDGES 1600000
#define D_IN    256
#define HS      32

#define NB      400    // row buckets
#define ROWS_PB 125    // rows per bucket (400*125 = 50000 exactly)
#define CAP     5120   // slots per bucket (mean 4000, std ~63 -> 17 sigma headroom)
#define EPB     4096   // edges per bin-phase block

// ---------------------------------------------------------------------------
// Kernel 1: fused Q/K/V projection with W staged in LDS (W thrashes L1
// otherwise). Q as [N][32]; K,V interleaved as float2[N][32] so the aggregate
// does one 8B gather per (edge,lane).
// ---------------------------------------------------------------------------
__global__ __launch_bounds__(256) void proj_kernel(
    const float* __restrict__ X,  const float* __restrict__ Wq,
    const float* __restrict__ Wk, const float* __restrict__ Wv,
    float* __restrict__ Q, float2* __restrict__ KV)
{
    __shared__ float wlds[128 * 96];   // 48 KB: [kk 0..127][mat*32+j]

    const int t = threadIdx.x;
    const int j = t & 31;
    const int g = t >> 5;
    const int row0 = blockIdx.x * 64 + g * 8;

    float acc[3][8];
#pragma unroll
    for (int m = 0; m < 3; m++)
#pragma unroll
        for (int i = 0; i < 8; i++) acc[m][i] = 0.f;

    int rows[8];
#pragma unroll
    for (int i = 0; i < 8; i++) {
        int r = row0 + i;
        rows[i] = (r < N_NODES) ? r : (N_NODES - 1);  // clamp; OOB never stored
    }

    for (int chunk = 0; chunk < 2; chunk++) {
        __syncthreads();
        for (int idx = t; idx < 128 * 32; idx += 256) {
            const int kk = idx >> 5, jj = idx & 31;
            const int k = chunk * 128 + kk;
            wlds[kk * 96 + jj]      = Wq[k * HS + jj];
            wlds[kk * 96 + 32 + jj] = Wk[k * HS + jj];
            wlds[kk * 96 + 64 + jj] = Wv[k * HS + jj];
        }
        __syncthreads();

        for (int k4 = 0; k4 < 32; k4++) {
            float4 xv[8];
#pragma unroll
            for (int i = 0; i < 8; i++)
                xv[i] = *(const float4*)(X + (size_t)rows[i] * D_IN
                                           + chunk * 128 + k4 * 4);
#pragma unroll
            for (int kk = 0; kk < 4; kk++) {
                const int kl = (k4 * 4 + kk) * 96;
                const float wq = wlds[kl + j];
                const float wk = wlds[kl + 32 + j];
                const float wv = wlds[kl + 64 + j];
#pragma unroll
                for (int i = 0; i < 8; i++) {
                    const float x = ((const float*)&xv[i])[kk];
                    acc[0][i] += x * wq;
                    acc[1][i] += x * wk;
                    acc[2][i] += x * wv;
                }
            }
        }
    }
#pragma unroll
    for (int i = 0; i < 8; i++) {
        const int r = row0 + i;
        if (r < N_NODES) {
            Q[r * HS + j]  = acc[0][i];
            KV[r * HS + j] = make_float2(acc[1][i], acc[2][i]);
        }
    }
}

// ---------------------------------------------------------------------------
// Phase A: bin edges into 400 row-buckets. LDS histogram -> one global claim
// per (block,bucket) -> packed write (local_row<<16 | col). Consecutive
// same-bucket edges of a block land in consecutive slots -> good line
// ownership, near-ideal writeback (vs 16x amplification of naive scatter).
// ---------------------------------------------------------------------------
__global__ __launch_bounds__(256) void bin_kernel(
    const int* __restrict__ er, const int* __restrict__ ec,
    int* __restrict__ fill, unsigned int* __restrict__ pairs)
{
    __shared__ int lcnt[NB];
    const int t  = threadIdx.x;
    const int e0 = blockIdx.x * EPB;
    const int e1 = min(e0 + EPB, N_EDGES);

    for (int b = t; b < NB; b += 256) lcnt[b] = 0;
    __syncthreads();

    for (int e = e0 + t; e < e1; e += 256)
        atomicAdd(&lcnt[er[e] / ROWS_PB], 1);
    __syncthreads();

    for (int b = t; b < NB; b += 256) {
        const int c = lcnt[b];
        lcnt[b] = (c > 0) ? atomicAdd(&fill[b], c) : 0;  // now holds base slot
    }
    __syncthreads();

    for (int e = e0 + t; e < e1; e += 256) {
        const int r = er[e];
        const int b = r / ROWS_PB;
        const int slot = atomicAdd(&lcnt[b], 1);
        pairs[(size_t)b * CAP + slot] =
            ((unsigned)(r - b * ROWS_PB) << 16) | (unsigned)ec[e];
    }
}

// ---------------------------------------------------------------------------
// Exclusive scan of the 400 bucket counts (1 block, LDS only).
// ---------------------------------------------------------------------------
__global__ __launch_bounds__(512) void scanfill_kernel(
    const int* __restrict__ fill, int* __restrict__ bstart,
    int* __restrict__ rowptr)
{
    __shared__ int s[512];
    const int t = threadIdx.x;
    const int v = (t < NB) ? fill[t] : 0;
    s[t] = v;
    __syncthreads();
#pragma unroll
    for (int ofs = 1; ofs < 512; ofs <<= 1) {
        const int u = (t >= ofs) ? s[t - ofs] : 0;
        __syncthreads();
        s[t] += u;
        __syncthreads();
    }
    if (t < NB) bstart[t] = s[t] - v;      // exclusive
    if (t == 0) rowptr[N_NODES] = N_EDGES; // every edge has a valid row
}

// ---------------------------------------------------------------------------
// Phase B: one block per bucket. Intra-bucket row histogram + scan in LDS,
// place cols into LDS staging, then one coalesced LDS->global copy.
// Also emits rowptr for this bucket's 125 rows. No global atomics.
// ---------------------------------------------------------------------------
__global__ __launch_bounds__(256) void place_kernel(
    const unsigned int* __restrict__ pairs, const int* __restrict__ fill,
    const int* __restrict__ bstart, int* __restrict__ rowptr,
    int* __restrict__ col_sorted)
{
    __shared__ int cnt_l[ROWS_PB];
    __shared__ int s[128];
    __shared__ int stage[CAP];

    const int b = blockIdx.x;
    const int t = threadIdx.x;
    const int n = fill[b];
    const int base = bstart[b];
    const unsigned int* pb = pairs + (size_t)b * CAP;

    for (int i = t; i < ROWS_PB; i += 256) cnt_l[i] = 0;
    __syncthreads();

    for (int i = t; i < n; i += 256)
        atomicAdd(&cnt_l[pb[i] >> 16], 1);
    __syncthreads();

    // exclusive scan of 125 row counts (128-wide Hillis-Steele)
    if (t < 128) s[t] = (t < ROWS_PB) ? cnt_l[t] : 0;
    __syncthreads();
#pragma unroll
    for (int ofs = 1; ofs < 128; ofs <<= 1) {
        const int u = (t < 128 && t >= ofs) ? s[t - ofs] : 0;
        __syncthreads();
        if (t < 128) s[t] += u;
        __syncthreads();
    }
    int excl = 0;
    if (t < ROWS_PB) {
        excl = s[t] - cnt_l[t];
        rowptr[b * ROWS_PB + t] = base + excl;
    }
    __syncthreads();
    if (t < ROWS_PB) cnt_l[t] = excl;   // becomes the placement cursor
    __syncthreads();

    for (int i = t; i < n; i += 256) {
        const unsigned p = pb[i];
        const int pos = atomicAdd(&cnt_l[p >> 16], 1);
        stage[pos] = (int)(p & 0xFFFFu);
    }
    __syncthreads();

    for (int i = t; i < n; i += 256)
        col_sorted[base + i] = stage[i];
}

// ---------------------------------------------------------------------------
// Aggregation: one wave per row; halves own alternate edges; KV gathered as
// float2; accumulation in registers; no atomics.
// ---------------------------------------------------------------------------
__global__ __launch_bounds__(256) void aggregate_kernel(
    const int* __restrict__ rowptr, const int* __restrict__ col,
    const float* __restrict__ Q, const float2* __restrict__ KV,
    float* __restrict__ out)
{
    const int lane = threadIdx.x & 63;
    const int r    = (blockIdx.x * blockDim.x + threadIdx.x) >> 6;  // wave id
    if (r >= N_NODES) return;
    const int j = lane & 31;
    const int h = lane >> 5;

    const float q = Q[r * HS + j];
    const int start = rowptr[r];
    const int end   = rowptr[r + 1];
    const float scale = 0.17677669529663687f;  // 1/sqrt(32)

    float accN = 0.f, accD = 0.f;
    int e = start + h;
    for (; e + 2 < end; e += 4) {
        const int c0 = col[e];
        const int c1 = col[e + 2];
        const float2 kv0 = KV[c0 * HS + j];
        const float2 kv1 = KV[c1 * HS + j];
        float p0 = q * kv0.x;
        float p1 = q * kv1.x;
#pragma unroll
        for (int ofs = 1; ofs < 32; ofs <<= 1) {
            p0 += __shfl_xor(p0, ofs, 64);
            p1 += __shfl_xor(p1, ofs, 64);
        }
        const float ex0 = __expf(p0 * scale);
        const float ex1 = __expf(p1 * scale);
        accD += ex0 + ex1;
        accN += ex0 * kv0.y + ex1 * kv1.y;
    }
    if (e < end) {
        const int c0 = col[e];
        const float2 kv0 = KV[c0 * HS + j];
        float p0 = q * kv0.x;
#pragma unroll
        for (int ofs = 1; ofs < 32; ofs <<= 1)
            p0 += __shfl_xor(p0, ofs, 64);
        const float ex0 = __expf(p0 * scale);
        accD += ex0;
        accN += ex0 * kv0.y;
    }
    accN += __shfl_xor(accN, 32, 64);
    accD += __shfl_xor(accD, 32, 64);
    if (h == 0)
        out[r * HS + j] = (accD > 0.f) ? accN / accD : 0.f;
}

extern "C" void kernel_launch(void* const* d_in, const int* in_sizes, int n_in,
                              void* d_out, int out_size, void* d_ws, size_t ws_size,
                              hipStream_t stream)
{
    const float* X  = (const float*)d_in[0];
    const float* Wq = (const float*)d_in[1];
    const float* Wk = (const float*)d_in[2];
    const float* Wv = (const float*)d_in[3];
    const int*   ei = (const int*)d_in[4];
    const int* er = ei;             // edge_index[0] (query rows)
    const int* ec = ei + N_EDGES;   // edge_index[1] (key/value cols)

    float* out = (float*)d_out;

    // workspace (~34 MB): Q | KV | fill | bstart | rowptr | pairs | col_sorted
    float*  Q        = (float*)d_ws;
    float2* KV       = (float2*)(Q + (size_t)N_NODES * HS);
    int* fill        = (int*)(KV + (size_t)N_NODES * HS);
    int* bstart      = fill + NB;
    int* rowptr      = bstart + NB;
    unsigned int* pairs = (unsigned int*)(rowptr + (N_NODES + 1));
    int* col_sorted  = (int*)(pairs + (size_t)NB * CAP);

    hipMemsetAsync(fill, 0, NB * sizeof(int), stream);

    proj_kernel<<<(N_NODES + 63) / 64, 256, 0, stream>>>(X, Wq, Wk, Wv, Q, KV);

    bin_kernel<<<(N_EDGES + EPB - 1) / EPB, 256, 0, stream>>>(er, ec, fill, pairs);
    scanfill_kernel<<<1, 512, 0, stream>>>(fill, bstart, rowptr);
    place_kernel<<<NB, 256, 0, stream>>>(pairs, fill, bstart, rowptr, col_sorted);

    aggregate_kernel<<<(N_NODES * 64 + 255) / 256, 256, 0, stream>>>(
        rowptr, col_sorted, Q, KV, out);
}

// Round 5
// 219.420 us; speedup vs baseline: 2.5844x; 1.2842x over previous
//
#include <hip/hip_runtime.h>

#define N_NODES 50000
#define N_EDGES 1600000
#define D_IN    256
#define HS      32

#define NB      400    // row buckets
#define ROWS_PB 125    // rows per bucket (400*125 = 50000 exactly)
#define CAP     5120   // slots per bucket (mean 4000, std ~63)
#define EPB     4096   // edges per bin-phase block

#define MTILE   128    // proj rows per block
#define XPITCH  264    // LDS row pitch in bf16 (256 + 8 pad = 528B, bank rot 4)

typedef __bf16 bf16x8 __attribute__((ext_vector_type(8)));
typedef float  floatx4 __attribute__((ext_vector_type(4)));

static __device__ __forceinline__ unsigned short f2bf(float f) {
    unsigned u = __float_as_uint(f);
    return (unsigned short)((u + 0x7FFFu + ((u >> 16) & 1u)) >> 16);  // RNE
}

// ---------------------------------------------------------------------------
// Pre-kernel: arrange [Wq|Wk|Wv] (fp32 [256,32] each) as bf16 B-fragments for
// mfma_f32_16x16x32_bf16. Layout: wfrag[(((s*6+t)*64+lane)*8)+j] =
// W[k = s*32 + (lane>>4)*8 + j][n = t*16 + (lane&15)] of the combined [256,96].
// 24576 elements; runs once, ~2us.
// ---------------------------------------------------------------------------
__global__ __launch_bounds__(256) void wfrag_kernel(
    const float* __restrict__ Wq, const float* __restrict__ Wk,
    const float* __restrict__ Wv, unsigned short* __restrict__ wfrag)
{
    const int i = blockIdx.x * blockDim.x + threadIdx.x;
    if (i >= 8 * 6 * 64 * 8) return;
    const int j    = i & 7;
    const int lane = (i >> 3) & 63;
    const int st   = i >> 9;
    const int t    = st % 6;
    const int s    = st / 6;
    const int k    = s * 32 + (lane >> 4) * 8 + j;
    const int col  = t * 16 + (lane & 15);
    float v;
    if      (col < 32) v = Wq[k * HS + col];
    else if (col < 64) v = Wk[k * HS + (col - 32)];
    else               v = Wv[k * HS + (col - 64)];
    wfrag[i] = f2bf(v);
}

// ---------------------------------------------------------------------------
// MFMA projection: [50000,256] x [256,96] in bf16 (fp32 accumulate).
// Block = 256 threads (4 waves), 128 rows. X tile staged fp32->bf16 in LDS
// ([row][k], pitch 264 bf16 -> 16B pad, 2-way bank alias = free). Wave w owns
// rows w*32..w*32+31: 2 M-subtiles x 6 N-tiles = 12 accumulators. K-loop: 8
// steps of 32. B fragments loaded coalesced from wfrag (L1/L2-hot, 48KB).
// Epilogue: C layout col=lane&15, row=(lane>>4)*4+i -> Q[n 0..31], KV.x/.y.
// ---------------------------------------------------------------------------
__global__ __launch_bounds__(256) void proj_mfma_kernel(
    const float* __restrict__ X, const unsigned short* __restrict__ wfrag,
    float* __restrict__ Q, float2* __restrict__ KV)
{
    __shared__ unsigned short xs[MTILE * XPITCH];   // 66 KB

    const int t    = threadIdx.x;
    const int lane = t & 63;
    const int w    = t >> 6;
    const int quad = lane >> 4;
    const int m16  = lane & 15;
    const int row0 = blockIdx.x * MTILE;

    // stage X tile: 128 rows x 64 float4; thread idx -> (row, c4); coalesced
    for (int it = 0; it < (MTILE * 64) / 256; it++) {
        const int idx = it * 256 + t;
        const int r   = idx >> 6;
        const int c4  = idx & 63;
        int gr = row0 + r;
        if (gr >= N_NODES) gr = N_NODES - 1;   // clamp; never stored
        const float4 xv = *(const float4*)(X + (size_t)gr * D_IN + c4 * 4);
        ushort4 b;
        b.x = f2bf(xv.x); b.y = f2bf(xv.y); b.z = f2bf(xv.z); b.w = f2bf(xv.w);
        *(ushort4*)(&xs[r * XPITCH + c4 * 4]) = b;
    }
    __syncthreads();

    floatx4 acc[2][6];
#pragma unroll
    for (int mt = 0; mt < 2; mt++)
#pragma unroll
        for (int nt = 0; nt < 6; nt++) acc[mt][nt] = (floatx4)0.f;

    const int arow[2] = { w * 32 + m16, w * 32 + 16 + m16 };

#pragma unroll
    for (int s = 0; s < 8; s++) {
        bf16x8 bfr[6];
#pragma unroll
        for (int nt = 0; nt < 6; nt++)
            bfr[nt] = *(const bf16x8*)(wfrag + (((s * 6 + nt) * 64 + lane) * 8));
        bf16x8 afr[2];
#pragma unroll
        for (int mt = 0; mt < 2; mt++)
            afr[mt] = *(const bf16x8*)(&xs[arow[mt] * XPITCH + s * 32 + quad * 8]);
#pragma unroll
        for (int mt = 0; mt < 2; mt++)
#pragma unroll
            for (int nt = 0; nt < 6; nt++)
                acc[mt][nt] = __builtin_amdgcn_mfma_f32_16x16x32_bf16(
                    afr[mt], bfr[nt], acc[mt][nt], 0, 0, 0);
    }

    // epilogue
#pragma unroll
    for (int mt = 0; mt < 2; mt++) {
#pragma unroll
        for (int i = 0; i < 4; i++) {
            const int gr = row0 + w * 32 + mt * 16 + quad * 4 + i;
            if (gr < N_NODES) {
                float* kvf = (float*)KV;
#pragma unroll
                for (int nt = 0; nt < 6; nt++) {
                    const int n = nt * 16 + m16;
                    const float v = acc[mt][nt][i];
                    if      (n < 32) Q[gr * HS + n] = v;
                    else if (n < 64) kvf[(gr * HS + (n - 32)) * 2]     = v;
                    else             kvf[(gr * HS + (n - 64)) * 2 + 1] = v;
                }
            }
        }
    }
}

// ---------------------------------------------------------------------------
// Phase A: bin edges into 400 row-buckets (LDS histogram -> one global claim
// per (block,bucket) -> packed (local_row<<16 | col) writes).
// ---------------------------------------------------------------------------
__global__ __launch_bounds__(256) void bin_kernel(
    const int* __restrict__ er, const int* __restrict__ ec,
    int* __restrict__ fill, unsigned int* __restrict__ pairs)
{
    __shared__ int lcnt[NB];
    const int t  = threadIdx.x;
    const int e0 = blockIdx.x * EPB;
    const int e1 = min(e0 + EPB, N_EDGES);

    for (int b = t; b < NB; b += 256) lcnt[b] = 0;
    __syncthreads();

    for (int e = e0 + t; e < e1; e += 256)
        atomicAdd(&lcnt[er[e] / ROWS_PB], 1);
    __syncthreads();

    for (int b = t; b < NB; b += 256) {
        const int c = lcnt[b];
        lcnt[b] = (c > 0) ? atomicAdd(&fill[b], c) : 0;  // base slot
    }
    __syncthreads();

    for (int e = e0 + t; e < e1; e += 256) {
        const int r = er[e];
        const int b = r / ROWS_PB;
        const int slot = atomicAdd(&lcnt[b], 1);
        pairs[(size_t)b * CAP + slot] =
            ((unsigned)(r - b * ROWS_PB) << 16) | (unsigned)ec[e];
    }
}

__global__ __launch_bounds__(512) void scanfill_kernel(
    const int* __restrict__ fill, int* __restrict__ bstart,
    int* __restrict__ rowptr)
{
    __shared__ int s[512];
    const int t = threadIdx.x;
    const int v = (t < NB) ? fill[t] : 0;
    s[t] = v;
    __syncthreads();
#pragma unroll
    for (int ofs = 1; ofs < 512; ofs <<= 1) {
        const int u = (t >= ofs) ? s[t - ofs] : 0;
        __syncthreads();
        s[t] += u;
        __syncthreads();
    }
    if (t < NB) bstart[t] = s[t] - v;
    if (t == 0) rowptr[N_NODES] = N_EDGES;
}

// ---------------------------------------------------------------------------
// Phase B: one block per bucket; LDS row-histogram + scan + LDS staging, then
// coalesced copy-out. Emits rowptr.
// ---------------------------------------------------------------------------
__global__ __launch_bounds__(256) void place_kernel(
    const unsigned int* __restrict__ pairs, const int* __restrict__ fill,
    const int* __restrict__ bstart, int* __restrict__ rowptr,
    int* __restrict__ col_sorted)
{
    __shared__ int cnt_l[ROWS_PB];
    __shared__ int s[128];
    __shared__ int stage[CAP];

    const int b = blockIdx.x;
    const int t = threadIdx.x;
    const int n = fill[b];
    const int base = bstart[b];
    const unsigned int* pb = pairs + (size_t)b * CAP;

    for (int i = t; i < ROWS_PB; i += 256) cnt_l[i] = 0;
    __syncthreads();

    for (int i = t; i < n; i += 256)
        atomicAdd(&cnt_l[pb[i] >> 16], 1);
    __syncthreads();

    if (t < 128) s[t] = (t < ROWS_PB) ? cnt_l[t] : 0;
    __syncthreads();
#pragma unroll
    for (int ofs = 1; ofs < 128; ofs <<= 1) {
        const int u = (t < 128 && t >= ofs) ? s[t - ofs] : 0;
        __syncthreads();
        if (t < 128) s[t] += u;
        __syncthreads();
    }
    int excl = 0;
    if (t < ROWS_PB) {
        excl = s[t] - cnt_l[t];
        rowptr[b * ROWS_PB + t] = base + excl;
    }
    __syncthreads();
    if (t < ROWS_PB) cnt_l[t] = excl;
    __syncthreads();

    for (int i = t; i < n; i += 256) {
        const unsigned p = pb[i];
        const int pos = atomicAdd(&cnt_l[p >> 16], 1);
        stage[pos] = (int)(p & 0xFFFFu);
    }
    __syncthreads();

    for (int i = t; i < n; i += 256)
        col_sorted[base + i] = stage[i];
}

// ---------------------------------------------------------------------------
// Aggregation: one wave per row; halves own alternate edges; KV float2
// gathers; register accumulation; no atomics.
// ---------------------------------------------------------------------------
__global__ __launch_bounds__(256) void aggregate_kernel(
    const int* __restrict__ rowptr, const int* __restrict__ col,
    const float* __restrict__ Q, const float2* __restrict__ KV,
    float* __restrict__ out)
{
    const int lane = threadIdx.x & 63;
    const int r    = (blockIdx.x * blockDim.x + threadIdx.x) >> 6;
    if (r >= N_NODES) return;
    const int j = lane & 31;
    const int h = lane >> 5;

    const float q = Q[r * HS + j];
    const int start = rowptr[r];
    const int end   = rowptr[r + 1];
    const float scale = 0.17677669529663687f;  // 1/sqrt(32)

    float accN = 0.f, accD = 0.f;
    int e = start + h;
    for (; e + 2 < end; e += 4) {
        const int c0 = col[e];
        const int c1 = col[e + 2];
        const float2 kv0 = KV[c0 * HS + j];
        const float2 kv1 = KV[c1 * HS + j];
        float p0 = q * kv0.x;
        float p1 = q * kv1.x;
#pragma unroll
        for (int ofs = 1; ofs < 32; ofs <<= 1) {
            p0 += __shfl_xor(p0, ofs, 64);
            p1 += __shfl_xor(p1, ofs, 64);
        }
        const float ex0 = __expf(p0 * scale);
        const float ex1 = __expf(p1 * scale);
        accD += ex0 + ex1;
        accN += ex0 * kv0.y + ex1 * kv1.y;
    }
    if (e < end) {
        const int c0 = col[e];
        const float2 kv0 = KV[c0 * HS + j];
        float p0 = q * kv0.x;
#pragma unroll
        for (int ofs = 1; ofs < 32; ofs <<= 1)
            p0 += __shfl_xor(p0, ofs, 64);
        const float ex0 = __expf(p0 * scale);
        accD += ex0;
        accN += ex0 * kv0.y;
    }
    accN += __shfl_xor(accN, 32, 64);
    accD += __shfl_xor(accD, 32, 64);
    if (h == 0)
        out[r * HS + j] = (accD > 0.f) ? accN / accD : 0.f;
}

extern "C" void kernel_launch(void* const* d_in, const int* in_sizes, int n_in,
                              void* d_out, int out_size, void* d_ws, size_t ws_size,
                              hipStream_t stream)
{
    const float* X  = (const float*)d_in[0];
    const float* Wq = (const float*)d_in[1];
    const float* Wk = (const float*)d_in[2];
    const float* Wv = (const float*)d_in[3];
    const int*   ei = (const int*)d_in[4];
    const int* er = ei;
    const int* ec = ei + N_EDGES;

    float* out = (float*)d_out;

    // workspace: Q | KV | fill | bstart | rowptr | wfrag | pairs | col_sorted
    float*  Q        = (float*)d_ws;
    float2* KV       = (float2*)(Q + (size_t)N_NODES * HS);
    int* fill        = (int*)(KV + (size_t)N_NODES * HS);
    int* bstart      = fill + NB;
    int* rowptr      = bstart + NB;
    unsigned short* wfrag = (unsigned short*)(rowptr + (N_NODES + 1));
    unsigned int* pairs   = (unsigned int*)(wfrag + 8 * 6 * 64 * 8);
    int* col_sorted  = (int*)(pairs + (size_t)NB * CAP);

    hipMemsetAsync(fill, 0, NB * sizeof(int), stream);

    wfrag_kernel<<<(8 * 6 * 64 * 8 + 255) / 256, 256, 0, stream>>>(Wq, Wk, Wv, wfrag);
    proj_mfma_kernel<<<(N_NODES + MTILE - 1) / MTILE, 256, 0, stream>>>(X, wfrag, Q, KV);

    bin_kernel<<<(N_EDGES + EPB - 1) / EPB, 256, 0, stream>>>(er, ec, fill, pairs);
    scanfill_kernel<<<1, 512, 0, stream>>>(fill, bstart, rowptr);
    place_kernel<<<NB, 256, 0, stream>>>(pairs, fill, bstart, rowptr, col_sorted);

    aggregate_kernel<<<(N_NODES * 64 + 255) / 256, 256, 0, stream>>>(
        rowptr, col_sorted, Q, KV, out);
}

// Round 6
// 177.345 us; speedup vs baseline: 3.1976x; 1.2373x over previous
//
#include <hip/hip_runtime.h>

#define N_NODES 50000
#define N_EDGES 1600000
#define D_IN    256
#define HS      32

#define NB      400    // row buckets
#define ROWS_PB 125    // rows per bucket (400*125 = 50000 exactly)
#define CAP     5120   // slots per bucket (mean 4000, std ~63)
#define EPB     4096   // edges per bin-phase block

#define MTILE   64     // proj rows per block (782 blocks -> ~3/CU occupancy)
#define XPITCH  264    // LDS row pitch in bf16 (256 + 8 pad)

typedef __bf16 bf16x8 __attribute__((ext_vector_type(8)));
typedef float  floatx4 __attribute__((ext_vector_type(4)));

static __device__ __forceinline__ unsigned short f2bf(float f) {
    unsigned u = __float_as_uint(f);
    return (unsigned short)((u + 0x7FFFu + ((u >> 16) & 1u)) >> 16);  // RNE
}

// ---------------------------------------------------------------------------
// Pre-kernel: arrange [Wq|Wk|Wv] (fp32 [256,32] each) as bf16 B-fragments for
// mfma_f32_16x16x32_bf16. wfrag[(((s*6+t)*64+lane)*8)+j] =
// W[k = s*32 + (lane>>4)*8 + j][n = t*16 + (lane&15)] of combined [256,96].
// ---------------------------------------------------------------------------
__global__ __launch_bounds__(256) void wfrag_kernel(
    const float* __restrict__ Wq, const float* __restrict__ Wk,
    const float* __restrict__ Wv, unsigned short* __restrict__ wfrag)
{
    const int i = blockIdx.x * blockDim.x + threadIdx.x;
    if (i >= 8 * 6 * 64 * 8) return;
    const int j    = i & 7;
    const int lane = (i >> 3) & 63;
    const int st   = i >> 9;
    const int t    = st % 6;
    const int s    = st / 6;
    const int k    = s * 32 + (lane >> 4) * 8 + j;
    const int col  = t * 16 + (lane & 15);
    float v;
    if      (col < 32) v = Wq[k * HS + col];
    else if (col < 64) v = Wk[k * HS + (col - 32)];
    else               v = Wv[k * HS + (col - 64)];
    wfrag[i] = f2bf(v);
}

// ---------------------------------------------------------------------------
// MFMA projection: [50000,256] x [256,96] bf16, fp32 accumulate.
// Block = 256 threads (4 waves), 64 rows; wave w owns rows w*16..w*16+15
// (1 M-subtile x 6 N-tiles). Q written fp32; K,V packed bf16 into one uint
// (K hi16, V lo16) -> aggregate gathers 4B/elem instead of 8B.
// C layout: col=lane&15, row=(lane>>4)*4+i  [learn_hip m89].
// ---------------------------------------------------------------------------
__global__ __launch_bounds__(256) void proj_mfma_kernel(
    const float* __restrict__ X, const unsigned short* __restrict__ wfrag,
    float* __restrict__ Q, unsigned int* __restrict__ KVp)
{
    __shared__ unsigned short xs[MTILE * XPITCH];   // 33 KB

    const int t    = threadIdx.x;
    const int lane = t & 63;
    const int w    = t >> 6;
    const int quad = lane >> 4;
    const int m16  = lane & 15;
    const int row0 = blockIdx.x * MTILE;

    // stage X tile: 64 rows x 64 float4, fp32->bf16; coalesced
#pragma unroll
    for (int it = 0; it < (MTILE * 64) / 256; it++) {
        const int idx = it * 256 + t;
        const int r   = idx >> 6;
        const int c4  = idx & 63;
        int gr = row0 + r;
        if (gr >= N_NODES) gr = N_NODES - 1;   // clamp; never stored
        const float4 xv = *(const float4*)(X + (size_t)gr * D_IN + c4 * 4);
        ushort4 b;
        b.x = f2bf(xv.x); b.y = f2bf(xv.y); b.z = f2bf(xv.z); b.w = f2bf(xv.w);
        *(ushort4*)(&xs[r * XPITCH + c4 * 4]) = b;
    }
    __syncthreads();

    floatx4 acc[6];
#pragma unroll
    for (int nt = 0; nt < 6; nt++) acc[nt] = (floatx4)0.f;

    const int arow = w * 16 + m16;

#pragma unroll
    for (int s = 0; s < 8; s++) {
        bf16x8 bfr[6];
#pragma unroll
        for (int nt = 0; nt < 6; nt++)
            bfr[nt] = *(const bf16x8*)(wfrag + (((s * 6 + nt) * 64 + lane) * 8));
        const bf16x8 afr = *(const bf16x8*)(&xs[arow * XPITCH + s * 32 + quad * 8]);
#pragma unroll
        for (int nt = 0; nt < 6; nt++)
            acc[nt] = __builtin_amdgcn_mfma_f32_16x16x32_bf16(afr, bfr[nt], acc[nt], 0, 0, 0);
    }

    // epilogue: Q from nt 0..1; K (nt 2..3) pairs with V (nt 4..5) at same j
#pragma unroll
    for (int i = 0; i < 4; i++) {
        const int gr = row0 + w * 16 + quad * 4 + i;
        if (gr < N_NODES) {
#pragma unroll
            for (int nt = 0; nt < 2; nt++)
                Q[gr * HS + nt * 16 + m16] = acc[nt][i];
#pragma unroll
            for (int p = 0; p < 2; p++) {
                const int j = p * 16 + m16;
                const unsigned kb = f2bf(acc[2 + p][i]);
                const unsigned vb = f2bf(acc[4 + p][i]);
                KVp[gr * HS + j] = (kb << 16) | vb;
            }
        }
    }
}

// ---------------------------------------------------------------------------
// Phase A: bin edges into 400 row-buckets (LDS histogram -> one global claim
// per (block,bucket) -> packed (local_row<<16 | col) writes).
// ---------------------------------------------------------------------------
__global__ __launch_bounds__(256) void bin_kernel(
    const int* __restrict__ er, const int* __restrict__ ec,
    int* __restrict__ fill, unsigned int* __restrict__ pairs)
{
    __shared__ int lcnt[NB];
    const int t  = threadIdx.x;
    const int e0 = blockIdx.x * EPB;
    const int e1 = min(e0 + EPB, N_EDGES);

    for (int b = t; b < NB; b += 256) lcnt[b] = 0;
    __syncthreads();

    for (int e = e0 + t; e < e1; e += 256)
        atomicAdd(&lcnt[er[e] / ROWS_PB], 1);
    __syncthreads();

    for (int b = t; b < NB; b += 256) {
        const int c = lcnt[b];
        lcnt[b] = (c > 0) ? atomicAdd(&fill[b], c) : 0;  // base slot
    }
    __syncthreads();

    for (int e = e0 + t; e < e1; e += 256) {
        const int r = er[e];
        const int b = r / ROWS_PB;
        const int slot = atomicAdd(&lcnt[b], 1);
        pairs[(size_t)b * CAP + slot] =
            ((unsigned)(r - b * ROWS_PB) << 16) | (unsigned)ec[e];
    }
}

__global__ __launch_bounds__(512) void scanfill_kernel(
    const int* __restrict__ fill, int* __restrict__ bstart,
    int* __restrict__ rowptr)
{
    __shared__ int s[512];
    const int t = threadIdx.x;
    const int v = (t < NB) ? fill[t] : 0;
    s[t] = v;
    __syncthreads();
#pragma unroll
    for (int ofs = 1; ofs < 512; ofs <<= 1) {
        const int u = (t >= ofs) ? s[t - ofs] : 0;
        __syncthreads();
        s[t] += u;
        __syncthreads();
    }
    if (t < NB) bstart[t] = s[t] - v;
    if (t == 0) rowptr[N_NODES] = N_EDGES;
}

// ---------------------------------------------------------------------------
// Phase B: one block per bucket; LDS row-histogram + scan + LDS staging, then
// coalesced copy-out. Emits rowptr.
// ---------------------------------------------------------------------------
__global__ __launch_bounds__(256) void place_kernel(
    const unsigned int* __restrict__ pairs, const int* __restrict__ fill,
    const int* __restrict__ bstart, int* __restrict__ rowptr,
    int* __restrict__ col_sorted)
{
    __shared__ int cnt_l[ROWS_PB];
    __shared__ int s[128];
    __shared__ int stage[CAP];

    const int b = blockIdx.x;
    const int t = threadIdx.x;
    const int n = fill[b];
    const int base = bstart[b];
    const unsigned int* pb = pairs + (size_t)b * CAP;

    for (int i = t; i < ROWS_PB; i += 256) cnt_l[i] = 0;
    __syncthreads();

    for (int i = t; i < n; i += 256)
        atomicAdd(&cnt_l[pb[i] >> 16], 1);
    __syncthreads();

    if (t < 128) s[t] = (t < ROWS_PB) ? cnt_l[t] : 0;
    __syncthreads();
#pragma unroll
    for (int ofs = 1; ofs < 128; ofs <<= 1) {
        const int u = (t < 128 && t >= ofs) ? s[t - ofs] : 0;
        __syncthreads();
        if (t < 128) s[t] += u;
        __syncthreads();
    }
    int excl = 0;
    if (t < ROWS_PB) {
        excl = s[t] - cnt_l[t];
        rowptr[b * ROWS_PB + t] = base + excl;
    }
    __syncthreads();
    if (t < ROWS_PB) cnt_l[t] = excl;
    __syncthreads();

    for (int i = t; i < n; i += 256) {
        const unsigned p = pb[i];
        const int pos = atomicAdd(&cnt_l[p >> 16], 1);
        stage[pos] = (int)(p & 0xFFFFu);
    }
    __syncthreads();

    for (int i = t; i < n; i += 256)
        col_sorted[base + i] = stage[i];
}

// ---------------------------------------------------------------------------
// Aggregation: one wave per row. lane = slot*8 + comp: 8 edge-slots x 8
// component-groups (4 elems each). Per iteration 16 edges (2 batches of 8).
// Edge gather: 8 lanes x uint4 (16B) = 128B packed-bf16 row. Dot reduce over
// comp lanes = 3 shfl (masks 1,2,4); slot reduction once per row at the end
// (masks 8,16,32). K = hi16, V = lo16. No atomics.
// ---------------------------------------------------------------------------
__global__ __launch_bounds__(256) void aggregate_kernel(
    const int* __restrict__ rowptr, const int* __restrict__ col,
    const float* __restrict__ Q, const unsigned int* __restrict__ KVp,
    float* __restrict__ out)
{
    const int lane = threadIdx.x & 63;
    const int r    = (blockIdx.x * blockDim.x + threadIdx.x) >> 6;
    if (r >= N_NODES) return;
    const int comp = lane & 7;
    const int slot = lane >> 3;

    const float4 q4 = *(const float4*)(Q + r * HS + comp * 4);
    const int start = rowptr[r];
    const int end   = rowptr[r + 1];
    const float scale = 0.17677669529663687f;  // 1/sqrt(32)

    float accD = 0.f;
    float n0 = 0.f, n1 = 0.f, n2 = 0.f, n3 = 0.f;

    for (int e0 = start; e0 < end; e0 += 16) {
        const int last = end - 1;
        const int eA = e0 + slot;
        const int eB = e0 + 8 + slot;
        const int cA = col[min(eA, last)];
        const int cB = col[min(eB, last)];
        const uint4 kvA = *(const uint4*)(KVp + (size_t)cA * HS + comp * 4);
        const uint4 kvB = *(const uint4*)(KVp + (size_t)cB * HS + comp * 4);

        float pA = q4.x * __uint_as_float(kvA.x & 0xFFFF0000u)
                 + q4.y * __uint_as_float(kvA.y & 0xFFFF0000u)
                 + q4.z * __uint_as_float(kvA.z & 0xFFFF0000u)
                 + q4.w * __uint_as_float(kvA.w & 0xFFFF0000u);
        float pB = q4.x * __uint_as_float(kvB.x & 0xFFFF0000u)
                 + q4.y * __uint_as_float(kvB.y & 0xFFFF0000u)
                 + q4.z * __uint_as_float(kvB.z & 0xFFFF0000u)
                 + q4.w * __uint_as_float(kvB.w & 0xFFFF0000u);
#pragma unroll
        for (int ofs = 1; ofs < 8; ofs <<= 1) {
            pA += __shfl_xor(pA, ofs, 64);
            pB += __shfl_xor(pB, ofs, 64);
        }
        const float exA = (eA < end) ? __expf(pA * scale) : 0.f;
        const float exB = (eB < end) ? __expf(pB * scale) : 0.f;
        accD += exA + exB;
        n0 += exA * __uint_as_float(kvA.x << 16) + exB * __uint_as_float(kvB.x << 16);
        n1 += exA * __uint_as_float(kvA.y << 16) + exB * __uint_as_float(kvB.y << 16);
        n2 += exA * __uint_as_float(kvA.z << 16) + exB * __uint_as_float(kvB.z << 16);
        n3 += exA * __uint_as_float(kvA.w << 16) + exB * __uint_as_float(kvB.w << 16);
    }

    // reduce over the 8 slots
#pragma unroll
    for (int ofs = 8; ofs < 64; ofs <<= 1) {
        accD += __shfl_xor(accD, ofs, 64);
        n0 += __shfl_xor(n0, ofs, 64);
        n1 += __shfl_xor(n1, ofs, 64);
        n2 += __shfl_xor(n2, ofs, 64);
        n3 += __shfl_xor(n3, ofs, 64);
    }

    if (slot == 0) {
        const float inv = (accD > 0.f) ? 1.f / accD : 0.f;
        float4 o;
        o.x = n0 * inv; o.y = n1 * inv; o.z = n2 * inv; o.w = n3 * inv;
        *(float4*)(out + r * HS + comp * 4) = o;
    }
}

extern "C" void kernel_launch(void* const* d_in, const int* in_sizes, int n_in,
                              void* d_out, int out_size, void* d_ws, size_t ws_size,
                              hipStream_t stream)
{
    const float* X  = (const float*)d_in[0];
    const float* Wq = (const float*)d_in[1];
    const float* Wk = (const float*)d_in[2];
    const float* Wv = (const float*)d_in[3];
    const int*   ei = (const int*)d_in[4];
    const int* er = ei;
    const int* ec = ei + N_EDGES;

    float* out = (float*)d_out;

    // workspace: Q | KVp | fill | bstart | rowptr | wfrag | pairs | col_sorted
    float* Q          = (float*)d_ws;
    unsigned int* KVp = (unsigned int*)(Q + (size_t)N_NODES * HS);
    int* fill         = (int*)(KVp + (size_t)N_NODES * HS);
    int* bstart       = fill + NB;
    int* rowptr       = bstart + NB;
    unsigned short* wfrag = (unsigned short*)(rowptr + (N_NODES + 1));
    unsigned int* pairs   = (unsigned int*)(wfrag + 8 * 6 * 64 * 8);
    int* col_sorted   = (int*)(pairs + (size_t)NB * CAP);

    hipMemsetAsync(fill, 0, NB * sizeof(int), stream);

    wfrag_kernel<<<(8 * 6 * 64 * 8 + 255) / 256, 256, 0, stream>>>(Wq, Wk, Wv, wfrag);
    proj_mfma_kernel<<<(N_NODES + MTILE - 1) / MTILE, 256, 0, stream>>>(X, wfrag, Q, KVp);

    bin_kernel<<<(N_EDGES + EPB - 1) / EPB, 256, 0, stream>>>(er, ec, fill, pairs);
    scanfill_kernel<<<1, 512, 0, stream>>>(fill, bstart, rowptr);
    place_kernel<<<NB, 256, 0, stream>>>(pairs, fill, bstart, rowptr, col_sorted);

    aggregate_kernel<<<(N_NODES * 64 + 255) / 256, 256, 0, stream>>>(
        rowptr, col_sorted, Q, KVp, out);
}

// Round 7
// 165.497 us; speedup vs baseline: 3.4265x; 1.0716x over previous
//
#include <hip/hip_runtime.h>

#define N_NODES 50000
#define N_EDGES 1600000
#define D_IN    256
#define HS      32

#define NB      400    // row buckets
#define ROWS_PB 125    // rows per bucket (400*125 = 50000 exactly)
#define CAP     5120   // slots per bucket (mean 4000, std ~63)
#define EPB     4096   // edges per bin-phase block (16 per thread)

#define MTILE   64     // proj rows per block
#define XPITCH  264    // LDS row pitch in bf16 (256 + 8 pad)

typedef __bf16 bf16x8 __attribute__((ext_vector_type(8)));
typedef float  floatx4 __attribute__((ext_vector_type(4)));

static __device__ __forceinline__ unsigned short f2bf(float f) {
    unsigned u = __float_as_uint(f);
    return (unsigned short)((u + 0x7FFFu + ((u >> 16) & 1u)) >> 16);  // RNE
}

// ---------------------------------------------------------------------------
// Pre-kernel: W -> bf16 B-fragments for mfma_f32_16x16x32_bf16.
// wfrag[(((s*6+t)*64+lane)*8)+j] = W[k=s*32+(lane>>4)*8+j][n=t*16+(lane&15)]
// of combined [256,96]. Block 0 also zeroes `fill` and sets rowptr[N]
// (replaces a memset launch).
// ---------------------------------------------------------------------------
__global__ __launch_bounds__(256) void wfrag_kernel(
    const float* __restrict__ Wq, const float* __restrict__ Wk,
    const float* __restrict__ Wv, unsigned short* __restrict__ wfrag,
    int* __restrict__ fill, int* __restrict__ rowptr)
{
    if (blockIdx.x == 0) {
        for (int b = threadIdx.x; b < NB; b += 256) fill[b] = 0;
        if (threadIdx.x == 0) rowptr[N_NODES] = N_EDGES;
    }
    const int i = blockIdx.x * blockDim.x + threadIdx.x;
    if (i >= 8 * 6 * 64 * 8) return;
    const int j    = i & 7;
    const int lane = (i >> 3) & 63;
    const int st   = i >> 9;
    const int t    = st % 6;
    const int s    = st / 6;
    const int k    = s * 32 + (lane >> 4) * 8 + j;
    const int col  = t * 16 + (lane & 15);
    float v;
    if      (col < 32) v = Wq[k * HS + col];
    else if (col < 64) v = Wk[k * HS + (col - 32)];
    else               v = Wv[k * HS + (col - 64)];
    wfrag[i] = f2bf(v);
}

// ---------------------------------------------------------------------------
// MFMA projection: [50000,256] x [256,96] bf16, fp32 accumulate.
// 4 waves x 16 rows; 6 N-tiles/wave. Q fp32; K,V packed bf16 in one uint
// (K hi16, V lo16). C layout: col=lane&15, row=(lane>>4)*4+i [m89].
// ---------------------------------------------------------------------------
__global__ __launch_bounds__(256) void proj_mfma_kernel(
    const float* __restrict__ X, const unsigned short* __restrict__ wfrag,
    float* __restrict__ Q, unsigned int* __restrict__ KVp)
{
    __shared__ unsigned short xs[MTILE * XPITCH];   // 33 KB

    const int t    = threadIdx.x;
    const int lane = t & 63;
    const int w    = t >> 6;
    const int quad = lane >> 4;
    const int m16  = lane & 15;
    const int row0 = blockIdx.x * MTILE;

#pragma unroll
    for (int it = 0; it < (MTILE * 64) / 256; it++) {
        const int idx = it * 256 + t;
        const int r   = idx >> 6;
        const int c4  = idx & 63;
        int gr = row0 + r;
        if (gr >= N_NODES) gr = N_NODES - 1;   // clamp; never stored
        const float4 xv = *(const float4*)(X + (size_t)gr * D_IN + c4 * 4);
        ushort4 b;
        b.x = f2bf(xv.x); b.y = f2bf(xv.y); b.z = f2bf(xv.z); b.w = f2bf(xv.w);
        *(ushort4*)(&xs[r * XPITCH + c4 * 4]) = b;
    }
    __syncthreads();

    floatx4 acc[6];
#pragma unroll
    for (int nt = 0; nt < 6; nt++) acc[nt] = (floatx4)0.f;

    const int arow = w * 16 + m16;

#pragma unroll
    for (int s = 0; s < 8; s++) {
        bf16x8 bfr[6];
#pragma unroll
        for (int nt = 0; nt < 6; nt++)
            bfr[nt] = *(const bf16x8*)(wfrag + (((s * 6 + nt) * 64 + lane) * 8));
        const bf16x8 afr = *(const bf16x8*)(&xs[arow * XPITCH + s * 32 + quad * 8]);
#pragma unroll
        for (int nt = 0; nt < 6; nt++)
            acc[nt] = __builtin_amdgcn_mfma_f32_16x16x32_bf16(afr, bfr[nt], acc[nt], 0, 0, 0);
    }

#pragma unroll
    for (int i = 0; i < 4; i++) {
        const int gr = row0 + w * 16 + quad * 4 + i;
        if (gr < N_NODES) {
#pragma unroll
            for (int nt = 0; nt < 2; nt++)
                Q[gr * HS + nt * 16 + m16] = acc[nt][i];
#pragma unroll
            for (int p = 0; p < 2; p++) {
                const int j = p * 16 + m16;
                const unsigned kb = f2bf(acc[2 + p][i]);
                const unsigned vb = f2bf(acc[4 + p][i]);
                KVp[gr * HS + j] = (kb << 16) | vb;
            }
        }
    }
}

// ---------------------------------------------------------------------------
// Phase A: bin edges into 400 row-buckets. Each thread register-caches its 16
// edges (one global read of er/ec total); LDS histogram -> one global claim
// per (block,bucket) -> packed (local_row<<16 | col) writes from registers.
// ---------------------------------------------------------------------------
__global__ __launch_bounds__(256) void bin_kernel(
    const int* __restrict__ er, const int* __restrict__ ec,
    int* __restrict__ fill, unsigned int* __restrict__ pairs)
{
    __shared__ int lcnt[NB];
    const int t  = threadIdx.x;
    const int e0 = blockIdx.x * EPB;
    const int e1 = min(e0 + EPB, N_EDGES);

    for (int b = t; b < NB; b += 256) lcnt[b] = 0;
    __syncthreads();

    int rl[16], cl[16];
#pragma unroll
    for (int i = 0; i < 16; i++) {
        const int e = e0 + t + i * 256;
        if (e < e1) {
            rl[i] = er[e];
            cl[i] = ec[e];
            atomicAdd(&lcnt[rl[i] / ROWS_PB], 1);
        }
    }
    __syncthreads();

    for (int b = t; b < NB; b += 256) {
        const int c = lcnt[b];
        lcnt[b] = (c > 0) ? atomicAdd(&fill[b], c) : 0;  // base slot
    }
    __syncthreads();

#pragma unroll
    for (int i = 0; i < 16; i++) {
        const int e = e0 + t + i * 256;
        if (e < e1) {
            const int r = rl[i];
            const int b = r / ROWS_PB;
            const int slot = atomicAdd(&lcnt[b], 1);
            pairs[(size_t)b * CAP + slot] =
                ((unsigned)(r - b * ROWS_PB) << 16) | (unsigned)cl[i];
        }
    }
}

__global__ __launch_bounds__(512) void scanfill_kernel(
    const int* __restrict__ fill, int* __restrict__ bstart)
{
    __shared__ int s[512];
    const int t = threadIdx.x;
    const int v = (t < NB) ? fill[t] : 0;
    s[t] = v;
    __syncthreads();
#pragma unroll
    for (int ofs = 1; ofs < 512; ofs <<= 1) {
        const int u = (t >= ofs) ? s[t - ofs] : 0;
        __syncthreads();
        s[t] += u;
        __syncthreads();
    }
    if (t < NB) bstart[t] = s[t] - v;
}

// ---------------------------------------------------------------------------
// Phase B: one block per bucket; pairs register-cached (<=20/thread, fixed-
// trip unroll so no scratch); LDS row-histogram + scan + LDS staging; emits
// rowptr; coalesced copy-out.
// ---------------------------------------------------------------------------
__global__ __launch_bounds__(256) void place_kernel(
    const unsigned int* __restrict__ pairs, const int* __restrict__ fill,
    const int* __restrict__ bstart, int* __restrict__ rowptr,
    int* __restrict__ col_sorted)
{
    __shared__ int cnt_l[ROWS_PB];
    __shared__ int s[128];
    __shared__ int stage[CAP];

    const int b = blockIdx.x;
    const int t = threadIdx.x;
    const int n = fill[b];
    const int base = bstart[b];
    const unsigned int* pb = pairs + (size_t)b * CAP;

    for (int i = t; i < ROWS_PB; i += 256) cnt_l[i] = 0;
    __syncthreads();

    unsigned pl[20];
#pragma unroll
    for (int k = 0; k < 20; k++) {
        const int i = t + k * 256;
        if (i < n) {
            pl[k] = pb[i];
            atomicAdd(&cnt_l[pl[k] >> 16], 1);
        }
    }
    __syncthreads();

    if (t < 128) s[t] = (t < ROWS_PB) ? cnt_l[t] : 0;
    __syncthreads();
#pragma unroll
    for (int ofs = 1; ofs < 128; ofs <<= 1) {
        const int u = (t < 128 && t >= ofs) ? s[t - ofs] : 0;
        __syncthreads();
        if (t < 128) s[t] += u;
        __syncthreads();
    }
    int excl = 0;
    if (t < ROWS_PB) {
        excl = s[t] - cnt_l[t];
        rowptr[b * ROWS_PB + t] = base + excl;
    }
    __syncthreads();
    if (t < ROWS_PB) cnt_l[t] = excl;
    __syncthreads();

#pragma unroll
    for (int k = 0; k < 20; k++) {
        const int i = t + k * 256;
        if (i < n) {
            const unsigned p = pl[k];
            const int pos = atomicAdd(&cnt_l[p >> 16], 1);
            stage[pos] = (int)(p & 0xFFFFu);
        }
    }
    __syncthreads();

    for (int i = t; i < n; i += 256)
        col_sorted[base + i] = stage[i];
}

// ---------------------------------------------------------------------------
// Aggregation: one wave per row; lane = slot*8+comp. 32 edges per iteration
// as 4 guarded batches of 8 (guards are wave-uniform): all col loads issued,
// then all KV gathers, then compute — amortizes the col->KV dependent-load
// chain over 4x more edges. K = hi16, V = lo16. No atomics.
// ---------------------------------------------------------------------------
__global__ __launch_bounds__(256) void aggregate_kernel(
    const int* __restrict__ rowptr, const int* __restrict__ col,
    const float* __restrict__ Q, const unsigned int* __restrict__ KVp,
    float* __restrict__ out)
{
    const int lane = threadIdx.x & 63;
    const int r    = (blockIdx.x * blockDim.x + threadIdx.x) >> 6;
    if (r >= N_NODES) return;
    const int comp = lane & 7;
    const int slot = lane >> 3;

    const float4 q4 = *(const float4*)(Q + r * HS + comp * 4);
    const int start = rowptr[r];
    const int end   = rowptr[r + 1];
    const int last  = end - 1;
    const float scale = 0.17677669529663687f;  // 1/sqrt(32)

    float accD = 0.f;
    float n0 = 0.f, n1 = 0.f, n2 = 0.f, n3 = 0.f;

    for (int e0 = start; e0 < end; e0 += 32) {
        int   cc[4];
        uint4 kv[4];
#pragma unroll
        for (int b = 0; b < 4; b++)
            if (e0 + 8 * b < end)
                cc[b] = col[min(e0 + 8 * b + slot, last)];
#pragma unroll
        for (int b = 0; b < 4; b++)
            if (e0 + 8 * b < end)
                kv[b] = *(const uint4*)(KVp + (size_t)cc[b] * HS + comp * 4);
#pragma unroll
        for (int b = 0; b < 4; b++) {
            if (e0 + 8 * b < end) {
                float p = q4.x * __uint_as_float(kv[b].x & 0xFFFF0000u)
                        + q4.y * __uint_as_float(kv[b].y & 0xFFFF0000u)
                        + q4.z * __uint_as_float(kv[b].z & 0xFFFF0000u)
                        + q4.w * __uint_as_float(kv[b].w & 0xFFFF0000u);
#pragma unroll
                for (int ofs = 1; ofs < 8; ofs <<= 1)
                    p += __shfl_xor(p, ofs, 64);
                const float ex = (e0 + 8 * b + slot < end) ? __expf(p * scale) : 0.f;
                accD += ex;
                n0 += ex * __uint_as_float(kv[b].x << 16);
                n1 += ex * __uint_as_float(kv[b].y << 16);
                n2 += ex * __uint_as_float(kv[b].z << 16);
                n3 += ex * __uint_as_float(kv[b].w << 16);
            }
        }
    }

    // reduce over the 8 slots
#pragma unroll
    for (int ofs = 8; ofs < 64; ofs <<= 1) {
        accD += __shfl_xor(accD, ofs, 64);
        n0 += __shfl_xor(n0, ofs, 64);
        n1 += __shfl_xor(n1, ofs, 64);
        n2 += __shfl_xor(n2, ofs, 64);
        n3 += __shfl_xor(n3, ofs, 64);
    }

    if (slot == 0) {
        const float inv = (accD > 0.f) ? 1.f / accD : 0.f;
        float4 o;
        o.x = n0 * inv; o.y = n1 * inv; o.z = n2 * inv; o.w = n3 * inv;
        *(float4*)(out + r * HS + comp * 4) = o;
    }
}

extern "C" void kernel_launch(void* const* d_in, const int* in_sizes, int n_in,
                              void* d_out, int out_size, void* d_ws, size_t ws_size,
                              hipStream_t stream)
{
    const float* X  = (const float*)d_in[0];
    const float* Wq = (const float*)d_in[1];
    const float* Wk = (const float*)d_in[2];
    const float* Wv = (const float*)d_in[3];
    const int*   ei = (const int*)d_in[4];
    const int* er = ei;
    const int* ec = ei + N_EDGES;

    float* out = (float*)d_out;

    // workspace: Q | KVp | fill | bstart | rowptr | wfrag | pairs | col_sorted
    float* Q          = (float*)d_ws;
    unsigned int* KVp = (unsigned int*)(Q + (size_t)N_NODES * HS);
    int* fill         = (int*)(KVp + (size_t)N_NODES * HS);
    int* bstart       = fill + NB;
    int* rowptr       = bstart + NB;
    unsigned short* wfrag = (unsigned short*)(rowptr + (N_NODES + 1));
    unsigned int* pairs   = (unsigned int*)(wfrag + 8 * 6 * 64 * 8);
    int* col_sorted   = (int*)(pairs + (size_t)NB * CAP);

    wfrag_kernel<<<(8 * 6 * 64 * 8 + 255) / 256, 256, 0, stream>>>(
        Wq, Wk, Wv, wfrag, fill, rowptr);
    proj_mfma_kernel<<<(N_NODES + MTILE - 1) / MTILE, 256, 0, stream>>>(X, wfrag, Q, KVp);

    bin_kernel<<<(N_EDGES + EPB - 1) / EPB, 256, 0, stream>>>(er, ec, fill, pairs);
    scanfill_kernel<<<1, 512, 0, stream>>>(fill, bstart);
    place_kernel<<<NB, 256, 0, stream>>>(pairs, fill, bstart, rowptr, col_sorted);

    aggregate_kernel<<<(N_NODES * 64 + 255) / 256, 256, 0, stream>>>(
        rowptr, col_sorted, Q, KVp, out);
}

// Round 8
// 158.661 us; speedup vs baseline: 3.5741x; 1.0431x over previous
//
#include <hip/hip_runtime.h>

#define N_NODES 50000
#define N_EDGES 1600000
#define D_IN    256
#define HS      32

#define NB      400    // row buckets
#define ROWS_PB 125    // rows per bucket (400*125 = 50000 exactly)
#define CAP     5120   // slots per bucket (mean 4000, std ~63)
#define EPB     4096   // edges per bin-phase block (16 per thread)

#define MTILE   64     // proj rows per block
#define XPITCH  264    // LDS row pitch in bf16 (256 + 8 pad)
#define PROJ_B  ((N_NODES + MTILE - 1) / MTILE)   // 782
#define BIN_B   ((N_EDGES + EPB - 1) / EPB)       // 391  (= PROJ_B/2 exactly)

typedef __bf16 bf16x8 __attribute__((ext_vector_type(8)));
typedef float  floatx4 __attribute__((ext_vector_type(4)));

static __device__ __forceinline__ unsigned short f2bf(float f) {
    unsigned u = __float_as_uint(f);
    return (unsigned short)((u + 0x7FFFu + ((u >> 16) & 1u)) >> 16);  // RNE
}

// ---------------------------------------------------------------------------
// Pre-kernel: W -> bf16 B-fragments for mfma_f32_16x16x32_bf16.
// wfrag[(((s*6+t)*64+lane)*8)+j] = W[k=s*32+(lane>>4)*8+j][n=t*16+(lane&15)]
// of combined [256,96]. Block 0 also zeroes `fill` and sets rowptr[N].
// ---------------------------------------------------------------------------
__global__ __launch_bounds__(256) void wfrag_kernel(
    const float* __restrict__ Wq, const float* __restrict__ Wk,
    const float* __restrict__ Wv, unsigned short* __restrict__ wfrag,
    int* __restrict__ fill, int* __restrict__ rowptr)
{
    if (blockIdx.x == 0) {
        for (int b = threadIdx.x; b < NB; b += 256) fill[b] = 0;
        if (threadIdx.x == 0) rowptr[N_NODES] = N_EDGES;
    }
    const int i = blockIdx.x * blockDim.x + threadIdx.x;
    if (i >= 8 * 6 * 64 * 8) return;
    const int j    = i & 7;
    const int lane = (i >> 3) & 63;
    const int st   = i >> 9;
    const int t    = st % 6;
    const int s    = st / 6;
    const int k    = s * 32 + (lane >> 4) * 8 + j;
    const int col  = t * 16 + (lane & 15);
    float v;
    if      (col < 32) v = Wq[k * HS + col];
    else if (col < 64) v = Wk[k * HS + (col - 32)];
    else               v = Wv[k * HS + (col - 64)];
    wfrag[i] = f2bf(v);
}

// ---------------------------------------------------------------------------
// Fused kernel: blocks with blockIdx%3 != 2 do the MFMA projection (782
// blocks); blocks with blockIdx%3 == 2 do edge binning (391 blocks). The two
// phases touch disjoint data (X/wfrag vs edge_index) so they overlap on the
// machine instead of serializing; interleaving mixes MFMA-heavy and
// VMEM-heavy blocks per CU (separate pipes co-schedule, m114).
// ---------------------------------------------------------------------------
__global__ __launch_bounds__(256) void proj_bin_kernel(
    const float* __restrict__ X, const unsigned short* __restrict__ wfrag,
    float* __restrict__ Q, unsigned int* __restrict__ KVp,
    const int* __restrict__ er, const int* __restrict__ ec,
    int* __restrict__ fill, unsigned int* __restrict__ pairs)
{
    __shared__ __align__(16) unsigned short xs[MTILE * XPITCH];   // 33 KB

    const int t = threadIdx.x;
    const int mod = blockIdx.x % 3;

    if (mod != 2) {
        // ---------------- projection ----------------
        const int pb   = (blockIdx.x / 3) * 2 + mod;
        const int lane = t & 63;
        const int w    = t >> 6;
        const int quad = lane >> 4;
        const int m16  = lane & 15;
        const int row0 = pb * MTILE;

#pragma unroll
        for (int it = 0; it < (MTILE * 64) / 256; it++) {
            const int idx = it * 256 + t;
            const int r   = idx >> 6;
            const int c4  = idx & 63;
            int gr = row0 + r;
            if (gr >= N_NODES) gr = N_NODES - 1;   // clamp; never stored
            const float4 xv = *(const float4*)(X + (size_t)gr * D_IN + c4 * 4);
            ushort4 b;
            b.x = f2bf(xv.x); b.y = f2bf(xv.y); b.z = f2bf(xv.z); b.w = f2bf(xv.w);
            *(ushort4*)(&xs[r * XPITCH + c4 * 4]) = b;
        }
        __syncthreads();

        floatx4 acc[6];
#pragma unroll
        for (int nt = 0; nt < 6; nt++) acc[nt] = (floatx4)0.f;

        const int arow = w * 16 + m16;

#pragma unroll
        for (int s = 0; s < 8; s++) {
            bf16x8 bfr[6];
#pragma unroll
            for (int nt = 0; nt < 6; nt++)
                bfr[nt] = *(const bf16x8*)(wfrag + (((s * 6 + nt) * 64 + lane) * 8));
            const bf16x8 afr = *(const bf16x8*)(&xs[arow * XPITCH + s * 32 + quad * 8]);
#pragma unroll
            for (int nt = 0; nt < 6; nt++)
                acc[nt] = __builtin_amdgcn_mfma_f32_16x16x32_bf16(afr, bfr[nt], acc[nt], 0, 0, 0);
        }

#pragma unroll
        for (int i = 0; i < 4; i++) {
            const int gr = row0 + w * 16 + quad * 4 + i;
            if (gr < N_NODES) {
#pragma unroll
                for (int nt = 0; nt < 2; nt++)
                    Q[gr * HS + nt * 16 + m16] = acc[nt][i];
#pragma unroll
                for (int p = 0; p < 2; p++) {
                    const int j = p * 16 + m16;
                    const unsigned kb = f2bf(acc[2 + p][i]);
                    const unsigned vb = f2bf(acc[4 + p][i]);
                    KVp[gr * HS + j] = (kb << 16) | vb;
                }
            }
        }
    } else {
        // ---------------- edge binning ----------------
        int* lcnt = (int*)xs;   // reuse LDS (block-uniform branch)
        const int bb = blockIdx.x / 3;
        const int e0 = bb * EPB;
        const int e1 = min(e0 + EPB, N_EDGES);

        for (int b = t; b < NB; b += 256) lcnt[b] = 0;
        __syncthreads();

        int rl[16], cl[16];
#pragma unroll
        for (int i = 0; i < 16; i++) {
            const int e = e0 + t + i * 256;
            if (e < e1) {
                rl[i] = er[e];
                cl[i] = ec[e];
                atomicAdd(&lcnt[rl[i] / ROWS_PB], 1);
            }
        }
        __syncthreads();

        for (int b = t; b < NB; b += 256) {
            const int c = lcnt[b];
            lcnt[b] = (c > 0) ? atomicAdd(&fill[b], c) : 0;  // base slot
        }
        __syncthreads();

#pragma unroll
        for (int i = 0; i < 16; i++) {
            const int e = e0 + t + i * 256;
            if (e < e1) {
                const int r = rl[i];
                const int b = r / ROWS_PB;
                const int slot = atomicAdd(&lcnt[b], 1);
                pairs[(size_t)b * CAP + slot] =
                    ((unsigned)(r - b * ROWS_PB) << 16) | (unsigned)cl[i];
            }
        }
    }
}

// ---------------------------------------------------------------------------
// Phase B: one block per bucket. Computes its own base offset (reduction of
// fill[0..b-1], L2-broadcast — replaces the scanfill dispatch), then LDS
// row-histogram + scan + staging; emits rowptr; coalesced copy-out.
// ---------------------------------------------------------------------------
__global__ __launch_bounds__(256) void place_kernel(
    const unsigned int* __restrict__ pairs, const int* __restrict__ fill,
    int* __restrict__ rowptr, int* __restrict__ col_sorted)
{
    __shared__ int cnt_l[ROWS_PB];
    __shared__ int s[128];
    __shared__ int red[256];
    __shared__ int stage[CAP];

    const int b = blockIdx.x;
    const int t = threadIdx.x;
    const int n = fill[b];
    const unsigned int* pb = pairs + (size_t)b * CAP;

    // base = sum of fill[0..b-1]
    int partial = 0;
    for (int i = t; i < b; i += 256) partial += fill[i];
    red[t] = partial;
    for (int i = t; i < ROWS_PB; i += 256) cnt_l[i] = 0;
    __syncthreads();
#pragma unroll
    for (int ofs = 128; ofs > 0; ofs >>= 1) {
        if (t < ofs) red[t] += red[t + ofs];
        __syncthreads();
    }
    const int base = red[0];

    unsigned pl[20];
#pragma unroll
    for (int k = 0; k < 20; k++) {
        const int i = t + k * 256;
        if (i < n) {
            pl[k] = pb[i];
            atomicAdd(&cnt_l[pl[k] >> 16], 1);
        }
    }
    __syncthreads();

    if (t < 128) s[t] = (t < ROWS_PB) ? cnt_l[t] : 0;
    __syncthreads();
#pragma unroll
    for (int ofs = 1; ofs < 128; ofs <<= 1) {
        const int u = (t < 128 && t >= ofs) ? s[t - ofs] : 0;
        __syncthreads();
        if (t < 128) s[t] += u;
        __syncthreads();
    }
    int excl = 0;
    if (t < ROWS_PB) {
        excl = s[t] - cnt_l[t];
        rowptr[b * ROWS_PB + t] = base + excl;
    }
    __syncthreads();
    if (t < ROWS_PB) cnt_l[t] = excl;
    __syncthreads();

#pragma unroll
    for (int k = 0; k < 20; k++) {
        const int i = t + k * 256;
        if (i < n) {
            const unsigned p = pl[k];
            const int pos = atomicAdd(&cnt_l[p >> 16], 1);
            stage[pos] = (int)(p & 0xFFFFu);
        }
    }
    __syncthreads();

    for (int i = t; i < n; i += 256)
        col_sorted[base + i] = stage[i];
}

// ---------------------------------------------------------------------------
// Aggregation: one wave per row; lane = slot*8+comp. 32 edges per iteration
// as 4 guarded batches of 8 (wave-uniform guards): col loads, then KV
// gathers, then compute. K = hi16, V = lo16. No atomics.
// ---------------------------------------------------------------------------
__global__ __launch_bounds__(256) void aggregate_kernel(
    const int* __restrict__ rowptr, const int* __restrict__ col,
    const float* __restrict__ Q, const unsigned int* __restrict__ KVp,
    float* __restrict__ out)
{
    const int lane = threadIdx.x & 63;
    const int r    = (blockIdx.x * blockDim.x + threadIdx.x) >> 6;
    if (r >= N_NODES) return;
    const int comp = lane & 7;
    const int slot = lane >> 3;

    const float4 q4 = *(const float4*)(Q + r * HS + comp * 4);
    const int start = rowptr[r];
    const int end   = rowptr[r + 1];
    const int last  = end - 1;
    const float scale = 0.17677669529663687f;  // 1/sqrt(32)

    float accD = 0.f;
    float n0 = 0.f, n1 = 0.f, n2 = 0.f, n3 = 0.f;

    for (int e0 = start; e0 < end; e0 += 32) {
        int   cc[4];
        uint4 kv[4];
#pragma unroll
        for (int b = 0; b < 4; b++)
            if (e0 + 8 * b < end)
                cc[b] = col[min(e0 + 8 * b + slot, last)];
#pragma unroll
        for (int b = 0; b < 4; b++)
            if (e0 + 8 * b < end)
                kv[b] = *(const uint4*)(KVp + (size_t)cc[b] * HS + comp * 4);
#pragma unroll
        for (int b = 0; b < 4; b++) {
            if (e0 + 8 * b < end) {
                float p = q4.x * __uint_as_float(kv[b].x & 0xFFFF0000u)
                        + q4.y * __uint_as_float(kv[b].y & 0xFFFF0000u)
                        + q4.z * __uint_as_float(kv[b].z & 0xFFFF0000u)
                        + q4.w * __uint_as_float(kv[b].w & 0xFFFF0000u);
#pragma unroll
                for (int ofs = 1; ofs < 8; ofs <<= 1)
                    p += __shfl_xor(p, ofs, 64);
                const float ex = (e0 + 8 * b + slot < end) ? __expf(p * scale) : 0.f;
                accD += ex;
                n0 += ex * __uint_as_float(kv[b].x << 16);
                n1 += ex * __uint_as_float(kv[b].y << 16);
                n2 += ex * __uint_as_float(kv[b].z << 16);
                n3 += ex * __uint_as_float(kv[b].w << 16);
            }
        }
    }

    // reduce over the 8 slots
#pragma unroll
    for (int ofs = 8; ofs < 64; ofs <<= 1) {
        accD += __shfl_xor(accD, ofs, 64);
        n0 += __shfl_xor(n0, ofs, 64);
        n1 += __shfl_xor(n1, ofs, 64);
        n2 += __shfl_xor(n2, ofs, 64);
        n3 += __shfl_xor(n3, ofs, 64);
    }

    if (slot == 0) {
        const float inv = (accD > 0.f) ? 1.f / accD : 0.f;
        float4 o;
        o.x = n0 * inv; o.y = n1 * inv; o.z = n2 * inv; o.w = n3 * inv;
        *(float4*)(out + r * HS + comp * 4) = o;
    }
}

extern "C" void kernel_launch(void* const* d_in, const int* in_sizes, int n_in,
                              void* d_out, int out_size, void* d_ws, size_t ws_size,
                              hipStream_t stream)
{
    const float* X  = (const float*)d_in[0];
    const float* Wq = (const float*)d_in[1];
    const float* Wk = (const float*)d_in[2];
    const float* Wv = (const float*)d_in[3];
    const int*   ei = (const int*)d_in[4];
    const int* er = ei;
    const int* ec = ei + N_EDGES;

    float* out = (float*)d_out;

    // workspace: Q | KVp | fill | rowptr | wfrag | pairs | col_sorted
    float* Q          = (float*)d_ws;
    unsigned int* KVp = (unsigned int*)(Q + (size_t)N_NODES * HS);
    int* fill         = (int*)(KVp + (size_t)N_NODES * HS);
    int* rowptr       = fill + NB;
    unsigned short* wfrag = (unsigned short*)(rowptr + (N_NODES + 1));
    unsigned int* pairs   = (unsigned int*)(wfrag + 8 * 6 * 64 * 8);
    int* col_sorted   = (int*)(pairs + (size_t)NB * CAP);

    wfrag_kernel<<<(8 * 6 * 64 * 8 + 255) / 256, 256, 0, stream>>>(
        Wq, Wk, Wv, wfrag, fill, rowptr);

    proj_bin_kernel<<<PROJ_B + BIN_B, 256, 0, stream>>>(
        X, wfrag, Q, KVp, er, ec, fill, pairs);

    place_kernel<<<NB, 256, 0, stream>>>(pairs, fill, rowptr, col_sorted);

    aggregate_kernel<<<(N_NODES * 64 + 255) / 256, 256, 0, stream>>>(
        rowptr, col_sorted, Q, KVp, out);
}